// Round 16
// baseline (359.338 us; speedup 1.0000x reference)
//
#include <hip/hip_runtime.h>

typedef unsigned short u16;
typedef __attribute__((ext_vector_type(8))) short s16x8;
typedef __attribute__((ext_vector_type(8))) unsigned short u16x8;
typedef __attribute__((ext_vector_type(4))) unsigned short u16x4;
typedef __attribute__((ext_vector_type(4))) float f32x4;

#define DEV __device__ __forceinline__

DEV u16 f2bf(float x) {
  union { float f; unsigned u; } c; c.f = x;
  unsigned r = c.u + 0x7FFFu + ((c.u >> 16) & 1u);
  return (u16)(r >> 16);
}
DEV float bf2f(u16 u) {
  union { unsigned u; float f; } c; c.u = ((unsigned)u) << 16;
  return c.f;
}
DEV void gload_lds16(const void* g, void* l) {
  __builtin_amdgcn_global_load_lds((const __attribute__((address_space(1))) void*)g,
                                   (__attribute__((address_space(3))) void*)l, 16, 0, 0);
}

// ---------------- RMSNorm: f32 [8192][2048] -> bf16 X ----------------
__global__ __launch_bounds__(256) void k_rmsnorm(const float* __restrict__ emb, u16* __restrict__ X) {
  const int row = blockIdx.x;
  const int t = threadIdx.x;
  const float4* p4 = (const float4*)(emb + (size_t)row * 2048);
  float4 v0 = p4[t * 2], v1 = p4[t * 2 + 1];
  float ss = v0.x * v0.x + v0.y * v0.y + v0.z * v0.z + v0.w * v0.w
           + v1.x * v1.x + v1.y * v1.y + v1.z * v1.z + v1.w * v1.w;
  for (int off = 32; off; off >>= 1) ss += __shfl_xor(ss, off);
  __shared__ float red[4];
  if ((t & 63) == 0) red[t >> 6] = ss;
  __syncthreads();
  float tot = red[0] + red[1] + red[2] + red[3];
  float inv = rsqrtf(tot * (1.0f / 2048.0f) + 1e-5f);
  float v[8] = {v0.x, v0.y, v0.z, v0.w, v1.x, v1.y, v1.z, v1.w};
  u16x8 o;
  for (int j = 0; j < 8; ++j) o[j] = f2bf(v[j] * inv);
  *(u16x8*)(X + (size_t)row * 2048 + t * 8) = o;
}

// ------------- transpose f32 [R][C] -> bf16 [C][dstStride] -------------
__global__ __launch_bounds__(256) void k_transpose(const float* __restrict__ src, u16* __restrict__ dst,
                                                   int C, int dstStride) {
  __shared__ float tile[32][33];
  const int bc = blockIdx.x * 32, br = blockIdx.y * 32;
  const int tx = threadIdx.x & 31, ty = threadIdx.x >> 5;
  for (int i = 0; i < 32; i += 8)
    tile[ty + i][tx] = src[(size_t)(br + ty + i) * C + bc + tx];
  __syncthreads();
  for (int i = 0; i < 32; i += 8)
    dst[(size_t)(bc + ty + i) * dstStride + br + tx] = f2bf(tile[tx][ty + i]);
}

// ------------- GEMM 256x256, BK=64, 8 waves — faithful m201 per-phase schedule -------------
// Per K-tile, 4 phases (one C-quadrant x K=64 each):
//   phase 0: stage half-A0(t+1) -> vmcnt(2) -> s_barrier -> 12 ds_reads (B all + A q0)
//   phase q>0: 4 A-frag ds_reads -> stage half (A1/B0/B1 of t+1) -> s_barrier
//   then: lgkmcnt(0) + sched_barrier(0) [rule #18] -> setprio(1) -> 16 MFMA -> setprio(0) -> s_barrier
// NO __syncthreads / NO vmcnt(0) in the main loop (T4). vmcnt(2) at tile top completes
// exactly tile t's 8 loads (2 newer in flight); per-thread vmcnt + barrier => all visible.
// Staging order A0,A1,B0,B1 gives HBM-sourced A 3-4 phases of latency budget, L2-hot B 1-2.
// RoPE-fused epilogue (R15): colmap(ni)=wn*16+ni*64 puts (d,d+64) pairs in-register.
template <int EPI>
__global__ __launch_bounds__(512) void k_gemm256(const u16* __restrict__ A, const u16* __restrict__ Bt,
                                                 const int N, const int K, const int NBN,
                                                 const float* __restrict__ cosb, const float* __restrict__ sinb,
                                                 u16* __restrict__ Qb, u16* __restrict__ Kb,
                                                 u16* __restrict__ VtOut,
                                                 const float* __restrict__ Emb, float* __restrict__ Cf) {
  __shared__ u16 Asm[2][256 * 64];
  __shared__ u16 Bsm[2][256 * 64];
  const int t = threadIdx.x, w = t >> 6, l = t & 63, g = (l >> 4), cc = l & 15;
  const int wm = w >> 2, wn = w & 3;

  const int lin = blockIdx.x;                  // natural order (best measured L2 behavior)
  const int bm = lin / NBN, bn = lin % NBN;
  const size_t m0 = (size_t)bm * 256, n0 = (size_t)bn * 256;

  const int srow = t >> 3, sch = t & 7;        // staging: row-within-64, 16B chunk

  // stage one half-tile (128 rows = 2 gload_lds per thread). which: 0=A rows0-127,
  // 1=A rows128-255, 2=B rows0-127, 3=B rows128-255.
  auto stageHalf = [&](int kt, int p, int which) {
    const u16* src = (which < 2) ? A : Bt;
    const size_t base0 = (which < 2) ? m0 : n0;
    u16* lds = (which < 2) ? &Asm[p][0] : &Bsm[p][0];
    const int h = (which & 1) * 128;
#pragma unroll
    for (int pass = 0; pass < 2; ++pass) {
      const int row = h + pass * 64 + srow;
      const int c2 = sch ^ (row & 7);
      gload_lds16(src + (base0 + row) * K + kt * 64 + c2 * 8, lds + row * 64 + sch * 8);
    }
  };

  f32x4 acc[8][4];
#pragma unroll
  for (int mi = 0; mi < 8; ++mi)
#pragma unroll
    for (int ni = 0; ni < 4; ++ni) acc[mi][ni] = (f32x4){0.f, 0.f, 0.f, 0.f};

  const int NT = K >> 6;
  // prologue: all 4 halves of tile 0
#pragma unroll
  for (int h = 0; h < 4; ++h) stageHalf(0, 0, h);

  for (int kt = 0; kt < NT; ++kt) {
    const int p = kt & 1;
    const bool pf = (kt + 1 < NT);
    const u16* Ap = &Asm[p][0];
    const u16* Bp = &Bsm[p][0];

    s16x8 bf[2][4];
#pragma unroll
    for (int q = 0; q < 4; ++q) {
      s16x8 af[2][2];
      if (q == 0) {
        // stage first, then counted wait + barrier, THEN the tile's first ds_reads
        if (pf) {
          stageHalf(kt + 1, p ^ 1, 0);
          asm volatile("s_waitcnt vmcnt(2)" ::: "memory");
        } else {
          asm volatile("s_waitcnt vmcnt(0)" ::: "memory");
        }
        __builtin_amdgcn_s_barrier();          // every thread's tile-t loads landed & visible
#pragma unroll
        for (int kk = 0; kk < 2; ++kk)
#pragma unroll
          for (int ni = 0; ni < 4; ++ni) {
            const int row = wn * 16 + ni * 64 + cc;
            bf[kk][ni] = *(const s16x8*)&Bp[row * 64 + (((kk * 4 + g) ^ (row & 7)) * 8)];
          }
#pragma unroll
        for (int kk = 0; kk < 2; ++kk)
#pragma unroll
          for (int m2 = 0; m2 < 2; ++m2) {
            const int row = wm * 128 + m2 * 16 + cc;
            af[kk][m2] = *(const s16x8*)&Ap[row * 64 + (((kk * 4 + g) ^ (row & 7)) * 8)];
          }
      } else {
        // ds_reads first (data guaranteed by phase-0 barrier), stage, then phase barrier
#pragma unroll
        for (int kk = 0; kk < 2; ++kk)
#pragma unroll
          for (int m2 = 0; m2 < 2; ++m2) {
            const int row = wm * 128 + (q * 2 + m2) * 16 + cc;
            af[kk][m2] = *(const s16x8*)&Ap[row * 64 + (((kk * 4 + g) ^ (row & 7)) * 8)];
          }
        if (pf) stageHalf(kt + 1, p ^ 1, q);
        __builtin_amdgcn_s_barrier();
      }
      asm volatile("s_waitcnt lgkmcnt(0)" ::: "memory");
      __builtin_amdgcn_sched_barrier(0);       // rule #18: fence MFMA behind the lgkm wait
      __builtin_amdgcn_s_setprio(1);
#pragma unroll
      for (int m2 = 0; m2 < 2; ++m2)
#pragma unroll
        for (int ni = 0; ni < 4; ++ni)
#pragma unroll
          for (int kk = 0; kk < 2; ++kk)
            acc[q * 2 + m2][ni] =
                __builtin_amdgcn_mfma_f32_16x16x32_bf16(af[kk][m2], bf[kk][ni], acc[q * 2 + m2][ni], 0, 0, 0);
      __builtin_amdgcn_s_setprio(0);
      __builtin_amdgcn_s_barrier();            // phase end: paces waves; seals buf reuse at q==3
    }
  }

  if (EPI == 1) {
#pragma unroll
    for (int mi = 0; mi < 8; ++mi)
#pragma unroll
      for (int ni = 0; ni < 4; ++ni)
#pragma unroll
        for (int r = 0; r < 4; ++r) {
          const size_t row = m0 + wm * 128 + mi * 16 + g * 4 + r;
          const size_t col = n0 + wn * 16 + ni * 64 + cc;
          Cf[row * N + col] = acc[mi][ni][r] + Emb[row * N + col];
        }
  } else if ((int)n0 < 2560) {
    // Q or K region: in-register RoPE on pairs (ni=2p, ni=2p+1), direct scatter.
    const bool isK = (int)n0 >= 2048;
    const float* cbase = cosb + (isK ? 524288 : 0);
    const float* sbase = sinb + (isK ? 524288 : 0);
    const int dlo = wn * 16 + cc;              // d in [0,64)
#pragma unroll
    for (int mi = 0; mi < 8; ++mi)
#pragma unroll
      for (int p = 0; p < 2; ++p) {
        const int colbase = (int)n0 + p * 128;   // head base col
#pragma unroll
        for (int r = 0; r < 4; ++r) {
          const int row = (int)m0 + wm * 128 + mi * 16 + g * 4 + r;
          const int bb = row >> 12, s = row & 4095;
          const float lo = acc[mi][2 * p + 0][r];
          const float hi = acc[mi][2 * p + 1][r];
          const float* cpr = cbase + (size_t)s * 128;
          const float* spr = sbase + (size_t)s * 128;
          const u16 olo = f2bf(cpr[dlo] * lo + spr[dlo] * hi);
          const u16 ohi = f2bf(cpr[dlo + 64] * hi + spr[dlo + 64] * lo);
          if (!isK) {
            const int h = colbase >> 7;          // 0..15
            u16* dq = Qb + ((size_t)(bb * 16 + h) * 4096 + s) * 128;
            dq[dlo] = olo;
            dq[dlo + 64] = ohi;
          } else {
            const int hkv = (colbase - 2048) >> 7;   // 0..3
            u16* dk = Kb + ((size_t)(bb * 4 + hkv) * 4096 + s) * 128;
            dk[dlo] = olo;
            dk[dlo + 64] = ohi;
          }
        }
      }
  } else {
    // V region: write V transposed Vt[b][hkv][d][4096]
    const int bb = (int)(m0 >> 12);
    const int s0base = (int)(m0 & 4095);
#pragma unroll
    for (int mi = 0; mi < 8; ++mi)
#pragma unroll
      for (int ni = 0; ni < 4; ++ni) {
        const int dcol = (int)(n0 - 2560) + wn * 16 + ni * 64 + cc;   // 0..511
        const int hkv = dcol >> 7, d = dcol & 127;
        const int s = s0base + wm * 128 + mi * 16 + g * 4;
        u16x4 o;
#pragma unroll
        for (int r = 0; r < 4; ++r) o[r] = f2bf(acc[mi][ni][r]);
        *(u16x4*)(VtOut + ((size_t)(bb * 4 + hkv) * 128 + d) * 4096 + s) = o;
      }
  }
}

// ------------- sliding-window flash attention, per-wave tile skip + fast path (R14) -------------
__global__ __launch_bounds__(256) void k_attn(const u16* __restrict__ Q, const u16* __restrict__ K,
                                              const u16* __restrict__ Vt, u16* __restrict__ AO) {
  const int bid = blockIdx.x;
  const int lin = (bid & 7) * 128 + (bid >> 3);   // XCD-pinned: group = bid&7
  const int grp = lin >> 7;
  const int b = grp >> 2, hkv = grp & 3;
  const int rem = lin & 127;
  const int h = hkv * 4 + (rem >> 5);
  const int qt = rem & 31;

  const int t = threadIdx.x, w = t >> 6, l = t & 63, g = l >> 4, cc = l & 15;
  const int q0 = qt * 128;
  const int myq0 = q0 + w * 32;                   // this wave's 32 q-rows
  const u16* Qp = Q + (((size_t)b * 16 + h) * 4096 + q0) * 128;
  const u16* Kp = K + ((size_t)b * 4 + hkv) * 4096 * 128;
  const u16* Vp = Vt + ((size_t)b * 4 + hkv) * 128 * 4096;

  __shared__ u16 Kl[2][32 * 128];   // [key][d], swizzled chunks (^row&7)
  __shared__ u16 Vl[2][128 * 32];   // [d][key], swizzled chunks (^d&3)
  __shared__ u16 Ps[4][32 * 40];    // per-wave P, stride 40 u16
  u16* myPs = &Ps[w][0];

  auto stage = [&](int kt, int bufi) {
    for (int pass = 0; pass < 2; ++pass) {
      const int m = pass * 256 + t;
      const int row = m >> 4, cst = m & 15;
      const int cor = cst ^ (row & 7);
      gload_lds16(Kp + (size_t)(kt * 32 + row) * 128 + cor * 8, &Kl[bufi][m * 8]);
    }
    for (int pass = 0; pass < 2; ++pass) {
      const int m = pass * 256 + t;
      const int d = m >> 2, cst = m & 3;
      const int cor = cst ^ (d & 3);
      gload_lds16(Vp + (size_t)d * 4096 + kt * 32 + cor * 8, &Vl[bufi][m * 8]);
    }
  };

  s16x8 qf[2][4];
  for (int mi = 0; mi < 2; ++mi)
    for (int kk = 0; kk < 4; ++kk)
      qf[mi][kk] = *(const s16x8*)(Qp + (size_t)(w * 32 + mi * 16 + cc) * 128 + kk * 32 + g * 8);

  f32x4 accO[2][8];
  for (int mi = 0; mi < 2; ++mi)
    for (int nd = 0; nd < 8; ++nd) accO[mi][nd] = (f32x4){0.f, 0.f, 0.f, 0.f};
  float mrun[2], lrun[2];
  for (int mi = 0; mi < 2; ++mi) { mrun[mi] = -1e30f; lrun[mi] = 0.f; }

  int lo = q0 - 511; if (lo < 0) lo = 0;
  const int kt_lo = lo >> 5, kt_hi = (q0 + 127) >> 5;
  const float scale = 0.08838834764831845f;

  int cur = 0;
  stage(kt_lo, 0);
  __syncthreads();

  for (int kt = kt_lo; kt <= kt_hi; ++kt) {
    if (kt < kt_hi) stage(kt + 1, cur ^ 1);

    const int k0 = kt * 32;
    const bool haswork = (k0 <= myq0 + 31) && (k0 + 31 >= myq0 - 511);
    const bool fullw   = (k0 + 31 <= myq0) && (k0 >= myq0 - 480);

    if (haswork) {
      f32x4 sc[2][2];
      for (int mi = 0; mi < 2; ++mi)
        for (int nk = 0; nk < 2; ++nk) sc[mi][nk] = (f32x4){0.f, 0.f, 0.f, 0.f};
      __builtin_amdgcn_s_setprio(1);
      for (int kk = 0; kk < 4; ++kk) {
        s16x8 kb[2];
        for (int nk = 0; nk < 2; ++nk) {
          const int row = nk * 16 + cc;
          kb[nk] = *(const s16x8*)&Kl[cur][row * 128 + (((kk * 4 + g) ^ (row & 7)) * 8)];
        }
        for (int mi = 0; mi < 2; ++mi)
          for (int nk = 0; nk < 2; ++nk)
            sc[mi][nk] = __builtin_amdgcn_mfma_f32_16x16x32_bf16(kb[nk], qf[mi][kk], sc[mi][nk], 0, 0, 0);
      }
      __builtin_amdgcn_s_setprio(0);

      for (int mi = 0; mi < 2; ++mi) {
        const int qpos = myq0 + mi * 16 + cc;
        if (fullw) {
          for (int nk = 0; nk < 2; ++nk)
            for (int r = 0; r < 4; ++r) sc[mi][nk][r] *= scale;
        } else {
          for (int nk = 0; nk < 2; ++nk)
            for (int r = 0; r < 4; ++r) {
              const int kpos = k0 + nk * 16 + g * 4 + r;
              const float v = sc[mi][nk][r] * scale;
              sc[mi][nk][r] = (kpos <= qpos && kpos + 512 > qpos) ? v : -1e30f;
            }
        }
        float rm = sc[mi][0][0];
        for (int nk = 0; nk < 2; ++nk)
          for (int r = 0; r < 4; ++r) rm = fmaxf(rm, sc[mi][nk][r]);
        rm = fmaxf(rm, __shfl_xor(rm, 16));
        rm = fmaxf(rm, __shfl_xor(rm, 32));
        const float mnew = fmaxf(mrun[mi], rm);
        float rs = 0.f;
        if (fullw) {
          for (int nk = 0; nk < 2; ++nk)
            for (int r = 0; r < 4; ++r) {
              float pv = __expf(sc[mi][nk][r] - mnew);
              sc[mi][nk][r] = pv;
              rs += pv;
            }
        } else {
          for (int nk = 0; nk < 2; ++nk)
            for (int r = 0; r < 4; ++r) {
              float pv = sc[mi][nk][r];
              pv = (pv <= -1e29f) ? 0.f : __expf(pv - mnew);  // guard: mnew may be -1e30
              sc[mi][nk][r] = pv;
              rs += pv;
            }
        }
        rs += __shfl_xor(rs, 16);
        rs += __shfl_xor(rs, 32);
        const float alpha = __expf(mrun[mi] - mnew);
        mrun[mi] = mnew;
        lrun[mi] = lrun[mi] * alpha + rs;
        for (int nd = 0; nd < 8; ++nd)
          for (int r = 0; r < 4; ++r) accO[mi][nd][r] *= alpha;
        for (int nk = 0; nk < 2; ++nk) {
          u16x4 o;
          for (int r = 0; r < 4; ++r) o[r] = f2bf(sc[mi][nk][r]);
          *(u16x4*)&myPs[(mi * 16 + cc) * 40 + nk * 16 + g * 4] = o;
        }
      }

      __builtin_amdgcn_s_setprio(1);
      {
        s16x8 pa[2];
        for (int mi = 0; mi < 2; ++mi)
          pa[mi] = *(const s16x8*)&myPs[(mi * 16 + cc) * 40 + g * 8];
        for (int nd = 0; nd < 8; ++nd) {
          const int d = nd * 16 + cc;
          s16x8 vb = *(const s16x8*)&Vl[cur][d * 32 + ((g ^ (d & 3)) * 8)];
          for (int mi = 0; mi < 2; ++mi)
            accO[mi][nd] = __builtin_amdgcn_mfma_f32_16x16x32_bf16(vb, pa[mi], accO[mi][nd], 0, 0, 0);
        }
      }
      __builtin_amdgcn_s_setprio(0);
    }

    __syncthreads();
    cur ^= 1;
  }

  u16* op = AO + ((size_t)b * 4096 + q0) * 2048 + (size_t)h * 128;
  for (int mi = 0; mi < 2; ++mi) {
    const float inv = 1.0f / lrun[mi];
    for (int nd = 0; nd < 8; ++nd) {
      u16x4 o;
      for (int r = 0; r < 4; ++r) o[r] = f2bf(accO[mi][nd][r] * inv);
      *(u16x4*)(op + (size_t)(w * 32 + mi * 16 + cc) * 2048 + nd * 16 + g * 4) = o;
    }
  }
}

extern "C" void kernel_launch(void* const* d_in, const int* in_sizes, int n_in,
                              void* d_out, int out_size, void* d_ws, size_t ws_size,
                              hipStream_t stream) {
  const float* emb  = (const float*)d_in[0];
  const float* cosb = (const float*)d_in[1];
  const float* sinb = (const float*)d_in[2];
  const float* wq   = (const float*)d_in[3];
  const float* wk   = (const float*)d_in[4];
  const float* wv   = (const float*)d_in[5];
  const float* wo   = (const float*)d_in[6];
  float* out = (float*)d_out;

  char* ws = (char*)d_ws;
  size_t off = 0;
  auto alloc = [&](size_t bytes) -> void* {
    void* p = ws + off;
    off += (bytes + 255) & ~(size_t)255;
    return p;
  };
  u16* X   = (u16*)alloc((size_t)8192 * 2048 * 2);   // normed bf16; reused as attn_out
  u16* Wt  = (u16*)alloc((size_t)3072 * 2048 * 2);   // [wq|wk|wv] transposed [n][k]
  u16* Wot = (u16*)alloc((size_t)2048 * 2048 * 2);   // wo transposed
  u16* Qb  = (u16*)alloc((size_t)2 * 16 * 4096 * 128 * 2);
  u16* Kb  = (u16*)alloc((size_t)2 * 4 * 4096 * 128 * 2);
  u16* VtB = (u16*)alloc((size_t)2 * 4 * 128 * 4096 * 2);  // V transposed [b][hkv][d][s]
  u16* AOb = X;  // X dead after GEMM1

  k_transpose<<<dim3(64, 64), 256, 0, stream>>>(wq, Wt, 2048, 2048);
  k_transpose<<<dim3(16, 64), 256, 0, stream>>>(wk, Wt + (size_t)2048 * 2048, 512, 2048);
  k_transpose<<<dim3(16, 64), 256, 0, stream>>>(wv, Wt + (size_t)2560 * 2048, 512, 2048);
  k_transpose<<<dim3(64, 64), 256, 0, stream>>>(wo, Wot, 2048, 2048);
  k_rmsnorm<<<8192, 256, 0, stream>>>(emb, X);
  // GEMM1: 8192x3072x2048, fused RoPE epilogue -> writes Qb/Kb/VtB directly (no qkv)
  k_gemm256<0><<<dim3(384), 512, 0, stream>>>(X, Wt, 3072, 2048, 12, cosb, sinb, Qb, Kb, VtB,
                                              nullptr, nullptr);
  k_attn<<<dim3(1024), 256, 0, stream>>>(Qb, Kb, VtB, AOb);
  // GEMM2: 8192x2048x2048 -> f32 out + residual
  k_gemm256<1><<<dim3(256), 512, 0, stream>>>(AOb, Wot, 2048, 2048, 8, nullptr, nullptr, nullptr, nullptr,
                                              nullptr, emb, out);
}

// Round 17
// 355.084 us; speedup vs baseline: 1.0120x; 1.0120x over previous
//
#include <hip/hip_runtime.h>

typedef unsigned short u16;
typedef __attribute__((ext_vector_type(8))) short s16x8;
typedef __attribute__((ext_vector_type(8))) unsigned short u16x8;
typedef __attribute__((ext_vector_type(4))) unsigned short u16x4;
typedef __attribute__((ext_vector_type(4))) float f32x4;

#define DEV __device__ __forceinline__

DEV u16 f2bf(float x) {
  union { float f; unsigned u; } c; c.f = x;
  unsigned r = c.u + 0x7FFFu + ((c.u >> 16) & 1u);
  return (u16)(r >> 16);
}
DEV float bf2f(u16 u) {
  union { unsigned u; float f; } c; c.u = ((unsigned)u) << 16;
  return c.f;
}
DEV void gload_lds16(const void* g, void* l) {
  __builtin_amdgcn_global_load_lds((const __attribute__((address_space(1))) void*)g,
                                   (__attribute__((address_space(3))) void*)l, 16, 0, 0);
}

// ---------------- RMSNorm: f32 [8192][2048] -> bf16 X ----------------
__global__ __launch_bounds__(256) void k_rmsnorm(const float* __restrict__ emb, u16* __restrict__ X) {
  const int row = blockIdx.x;
  const int t = threadIdx.x;
  const float4* p4 = (const float4*)(emb + (size_t)row * 2048);
  float4 v0 = p4[t * 2], v1 = p4[t * 2 + 1];
  float ss = v0.x * v0.x + v0.y * v0.y + v0.z * v0.z + v0.w * v0.w
           + v1.x * v1.x + v1.y * v1.y + v1.z * v1.z + v1.w * v1.w;
  for (int off = 32; off; off >>= 1) ss += __shfl_xor(ss, off);
  __shared__ float red[4];
  if ((t & 63) == 0) red[t >> 6] = ss;
  __syncthreads();
  float tot = red[0] + red[1] + red[2] + red[3];
  float inv = rsqrtf(tot * (1.0f / 2048.0f) + 1e-5f);
  float v[8] = {v0.x, v0.y, v0.z, v0.w, v1.x, v1.y, v1.z, v1.w};
  u16x8 o;
  for (int j = 0; j < 8; ++j) o[j] = f2bf(v[j] * inv);
  *(u16x8*)(X + (size_t)row * 2048 + t * 8) = o;
}

// ------------- transpose f32 [R][C] -> bf16 [C][dstStride] -------------
__global__ __launch_bounds__(256) void k_transpose(const float* __restrict__ src, u16* __restrict__ dst,
                                                   int C, int dstStride) {
  __shared__ float tile[32][33];
  const int bc = blockIdx.x * 32, br = blockIdx.y * 32;
  const int tx = threadIdx.x & 31, ty = threadIdx.x >> 5;
  for (int i = 0; i < 32; i += 8)
    tile[ty + i][tx] = src[(size_t)(br + ty + i) * C + bc + tx];
  __syncthreads();
  for (int i = 0; i < 32; i += 8)
    dst[(size_t)(bc + ty + i) * dstStride + br + tx] = f2bf(tile[tx][ty + i]);
}

// ------------- GEMM 256x256 tile, BK=64, 8 waves, barrier-free interior (R12/R15, FROZEN) -------------
// Four source-level pipelining attempts (R8/R10/R16 counted-vmcnt variants, R7 phase barriers)
// all regressed vs this compiler-scheduled interior; GEMM schedule work closed.
// colmap(ni) = wn*16 + ni*64: RoPE (d,d+64) pairs land in one thread's acc registers.
// EPI==0: n0<2048 rotate+write Q; n0<2560 rotate+write K; else V transposed.
// EPI==1: f32 C write + residual add.
template <int EPI>
__global__ __launch_bounds__(512) void k_gemm256(const u16* __restrict__ A, const u16* __restrict__ Bt,
                                                 const int N, const int K, const int NBN,
                                                 const float* __restrict__ cosb, const float* __restrict__ sinb,
                                                 u16* __restrict__ Qb, u16* __restrict__ Kb,
                                                 u16* __restrict__ VtOut,
                                                 const float* __restrict__ Emb, float* __restrict__ Cf) {
  __shared__ u16 Asm[2][256 * 64];
  __shared__ u16 Bsm[2][256 * 64];
  const int t = threadIdx.x, w = t >> 6, l = t & 63, g = (l >> 4), cc = l & 15;
  const int wm = w >> 2, wn = w & 3;

  const int lin = blockIdx.x;                  // natural order (best measured L2 behavior)
  const int bm = lin / NBN, bn = lin % NBN;
  const size_t m0 = (size_t)bm * 256, n0 = (size_t)bn * 256;

  const int srow = t >> 3, sch = t & 7;        // staging: row-within-64, 16B chunk

  auto stA = [&](int kt, int p, int pass) {
    const int row = pass * 64 + srow;
    const int c2 = sch ^ (row & 7);
    gload_lds16(A + (m0 + row) * K + kt * 64 + c2 * 8, &Asm[p][row * 64 + sch * 8]);
  };
  auto stB = [&](int kt, int p, int pass) {
    const int row = pass * 64 + srow;
    const int c2 = sch ^ (row & 7);
    gload_lds16(Bt + (n0 + row) * K + kt * 64 + c2 * 8, &Bsm[p][row * 64 + sch * 8]);
  };

  f32x4 acc[8][4];
#pragma unroll
  for (int mi = 0; mi < 8; ++mi)
#pragma unroll
    for (int ni = 0; ni < 4; ++ni) acc[mi][ni] = (f32x4){0.f, 0.f, 0.f, 0.f};

  const int NT = K >> 6;
#pragma unroll
  for (int pass = 0; pass < 4; ++pass) { stA(0, 0, pass); stB(0, 0, pass); }
  __syncthreads();

  for (int kt = 0; kt < NT; ++kt) {
    const int p = kt & 1;
    const bool pf = (kt + 1 < NT);
    const u16* Ap = &Asm[p][0];
    const u16* Bp = &Bsm[p][0];

    s16x8 bf[2][4];
#pragma unroll
    for (int kk = 0; kk < 2; ++kk)
#pragma unroll
      for (int ni = 0; ni < 4; ++ni) {
        const int row = wn * 16 + ni * 64 + cc;        // colmap
        bf[kk][ni] = *(const s16x8*)&Bp[row * 64 + (((kk * 4 + g) ^ (row & 7)) * 8)];
      }

#pragma unroll
    for (int q = 0; q < 4; ++q) {
      s16x8 af[2][2];
#pragma unroll
      for (int kk = 0; kk < 2; ++kk)
#pragma unroll
        for (int m2 = 0; m2 < 2; ++m2) {
          const int row = wm * 128 + (q * 2 + m2) * 16 + cc;
          af[kk][m2] = *(const s16x8*)&Ap[row * 64 + (((kk * 4 + g) ^ (row & 7)) * 8)];
        }
      if (pf) {   // 3/3/2/0 spread
        if (q == 0) { stA(kt + 1, p ^ 1, 0); stA(kt + 1, p ^ 1, 1); stB(kt + 1, p ^ 1, 0); }
        else if (q == 1) { stA(kt + 1, p ^ 1, 2); stA(kt + 1, p ^ 1, 3); stB(kt + 1, p ^ 1, 1); }
        else if (q == 2) { stB(kt + 1, p ^ 1, 2); stB(kt + 1, p ^ 1, 3); }
      }
      // barrier-free interior: compiler interleaves ds_read/MFMA/staging
#pragma unroll
      for (int m2 = 0; m2 < 2; ++m2)
#pragma unroll
        for (int ni = 0; ni < 4; ++ni)
#pragma unroll
          for (int kk = 0; kk < 2; ++kk)
            acc[q * 2 + m2][ni] =
                __builtin_amdgcn_mfma_f32_16x16x32_bf16(af[kk][m2], bf[kk][ni], acc[q * 2 + m2][ni], 0, 0, 0);
    }
    __syncthreads();   // the only barrier per tile
  }

  if (EPI == 1) {
#pragma unroll
    for (int mi = 0; mi < 8; ++mi)
#pragma unroll
      for (int ni = 0; ni < 4; ++ni)
#pragma unroll
        for (int r = 0; r < 4; ++r) {
          const size_t row = m0 + wm * 128 + mi * 16 + g * 4 + r;
          const size_t col = n0 + wn * 16 + ni * 64 + cc;
          Cf[row * N + col] = acc[mi][ni][r] + Emb[row * N + col];
        }
  } else if ((int)n0 < 2560) {
    // Q or K region: in-register RoPE on pairs (ni=2p, ni=2p+1), direct scatter.
    // cos/sin depend only on (s, d) -> hoisted out of the head (p) loop.
    const bool isK = (int)n0 >= 2048;
    const float* cbase = cosb + (isK ? 524288 : 0);
    const float* sbase = sinb + (isK ? 524288 : 0);
    const int dlo = wn * 16 + cc;              // d in [0,64)
#pragma unroll
    for (int mi = 0; mi < 8; ++mi)
#pragma unroll
      for (int r = 0; r < 4; ++r) {
        const int row = (int)m0 + wm * 128 + mi * 16 + g * 4 + r;
        const int bb = row >> 12, s = row & 4095;
        const float* cpr = cbase + (size_t)s * 128;
        const float* spr = sbase + (size_t)s * 128;
        const float cl = cpr[dlo], sl = spr[dlo];
        const float ch = cpr[dlo + 64], sh = spr[dlo + 64];
#pragma unroll
        for (int p = 0; p < 2; ++p) {
          const int colbase = (int)n0 + p * 128;   // head base col
          const float lo = acc[mi][2 * p + 0][r];
          const float hi = acc[mi][2 * p + 1][r];
          const u16 olo = f2bf(cl * lo + sl * hi);
          const u16 ohi = f2bf(ch * hi + sh * lo);
          if (!isK) {
            const int h = colbase >> 7;          // 0..15
            u16* dq = Qb + ((size_t)(bb * 16 + h) * 4096 + s) * 128;
            dq[dlo] = olo;
            dq[dlo + 64] = ohi;
          } else {
            const int hkv = (colbase - 2048) >> 7;   // 0..3
            u16* dk = Kb + ((size_t)(bb * 4 + hkv) * 4096 + s) * 128;
            dk[dlo] = olo;
            dk[dlo + 64] = ohi;
          }
        }
      }
  } else {
    // V region: write V transposed Vt[b][hkv][d][4096]
    const int bb = (int)(m0 >> 12);
    const int s0base = (int)(m0 & 4095);
#pragma unroll
    for (int mi = 0; mi < 8; ++mi)
#pragma unroll
      for (int ni = 0; ni < 4; ++ni) {
        const int dcol = (int)(n0 - 2560) + wn * 16 + ni * 64 + cc;   // 0..511
        const int hkv = dcol >> 7, d = dcol & 127;
        const int s = s0base + wm * 128 + mi * 16 + g * 4;
        u16x4 o;
#pragma unroll
        for (int r = 0; r < 4; ++r) o[r] = f2bf(acc[mi][ni][r]);
        *(u16x4*)(VtOut + ((size_t)(bb * 4 + hkv) * 128 + d) * 4096 + s) = o;
      }
  }
}

// ------------- sliding-window flash attention, per-wave tile skip + fast path (R14) -------------
__global__ __launch_bounds__(256) void k_attn(const u16* __restrict__ Q, const u16* __restrict__ K,
                                              const u16* __restrict__ Vt, u16* __restrict__ AO) {
  const int bid = blockIdx.x;
  const int lin = (bid & 7) * 128 + (bid >> 3);   // XCD-pinned: group = bid&7
  const int grp = lin >> 7;
  const int b = grp >> 2, hkv = grp & 3;
  const int rem = lin & 127;
  const int h = hkv * 4 + (rem >> 5);
  const int qt = rem & 31;

  const int t = threadIdx.x, w = t >> 6, l = t & 63, g = l >> 4, cc = l & 15;
  const int q0 = qt * 128;
  const int myq0 = q0 + w * 32;                   // this wave's 32 q-rows
  const u16* Qp = Q + (((size_t)b * 16 + h) * 4096 + q0) * 128;
  const u16* Kp = K + ((size_t)b * 4 + hkv) * 4096 * 128;
  const u16* Vp = Vt + ((size_t)b * 4 + hkv) * 128 * 4096;

  __shared__ u16 Kl[2][32 * 128];   // [key][d], swizzled chunks (^row&7)
  __shared__ u16 Vl[2][128 * 32];   // [d][key], swizzled chunks (^d&3)
  __shared__ u16 Ps[4][32 * 40];    // per-wave P, stride 40 u16
  u16* myPs = &Ps[w][0];

  auto stage = [&](int kt, int bufi) {
    for (int pass = 0; pass < 2; ++pass) {
      const int m = pass * 256 + t;
      const int row = m >> 4, cst = m & 15;
      const int cor = cst ^ (row & 7);
      gload_lds16(Kp + (size_t)(kt * 32 + row) * 128 + cor * 8, &Kl[bufi][m * 8]);
    }
    for (int pass = 0; pass < 2; ++pass) {
      const int m = pass * 256 + t;
      const int d = m >> 2, cst = m & 3;
      const int cor = cst ^ (d & 3);
      gload_lds16(Vp + (size_t)d * 4096 + kt * 32 + cor * 8, &Vl[bufi][m * 8]);
    }
  };

  s16x8 qf[2][4];
  for (int mi = 0; mi < 2; ++mi)
    for (int kk = 0; kk < 4; ++kk)
      qf[mi][kk] = *(const s16x8*)(Qp + (size_t)(w * 32 + mi * 16 + cc) * 128 + kk * 32 + g * 8);

  f32x4 accO[2][8];
  for (int mi = 0; mi < 2; ++mi)
    for (int nd = 0; nd < 8; ++nd) accO[mi][nd] = (f32x4){0.f, 0.f, 0.f, 0.f};
  float mrun[2], lrun[2];
  for (int mi = 0; mi < 2; ++mi) { mrun[mi] = -1e30f; lrun[mi] = 0.f; }

  int lo = q0 - 511; if (lo < 0) lo = 0;
  const int kt_lo = lo >> 5, kt_hi = (q0 + 127) >> 5;
  const float scale = 0.08838834764831845f;

  int cur = 0;
  stage(kt_lo, 0);
  __syncthreads();

  for (int kt = kt_lo; kt <= kt_hi; ++kt) {
    if (kt < kt_hi) stage(kt + 1, cur ^ 1);

    const int k0 = kt * 32;
    const bool haswork = (k0 <= myq0 + 31) && (k0 + 31 >= myq0 - 511);
    const bool fullw   = (k0 + 31 <= myq0) && (k0 >= myq0 - 480);

    if (haswork) {
      f32x4 sc[2][2];
      for (int mi = 0; mi < 2; ++mi)
        for (int nk = 0; nk < 2; ++nk) sc[mi][nk] = (f32x4){0.f, 0.f, 0.f, 0.f};
      __builtin_amdgcn_s_setprio(1);
      for (int kk = 0; kk < 4; ++kk) {
        s16x8 kb[2];
        for (int nk = 0; nk < 2; ++nk) {
          const int row = nk * 16 + cc;
          kb[nk] = *(const s16x8*)&Kl[cur][row * 128 + (((kk * 4 + g) ^ (row & 7)) * 8)];
        }
        for (int mi = 0; mi < 2; ++mi)
          for (int nk = 0; nk < 2; ++nk)
            sc[mi][nk] = __builtin_amdgcn_mfma_f32_16x16x32_bf16(kb[nk], qf[mi][kk], sc[mi][nk], 0, 0, 0);
      }
      __builtin_amdgcn_s_setprio(0);

      for (int mi = 0; mi < 2; ++mi) {
        const int qpos = myq0 + mi * 16 + cc;
        if (fullw) {
          for (int nk = 0; nk < 2; ++nk)
            for (int r = 0; r < 4; ++r) sc[mi][nk][r] *= scale;
        } else {
          for (int nk = 0; nk < 2; ++nk)
            for (int r = 0; r < 4; ++r) {
              const int kpos = k0 + nk * 16 + g * 4 + r;
              const float v = sc[mi][nk][r] * scale;
              sc[mi][nk][r] = (kpos <= qpos && kpos + 512 > qpos) ? v : -1e30f;
            }
        }
        float rm = sc[mi][0][0];
        for (int nk = 0; nk < 2; ++nk)
          for (int r = 0; r < 4; ++r) rm = fmaxf(rm, sc[mi][nk][r]);
        rm = fmaxf(rm, __shfl_xor(rm, 16));
        rm = fmaxf(rm, __shfl_xor(rm, 32));
        const float mnew = fmaxf(mrun[mi], rm);
        float rs = 0.f;
        if (fullw) {
          for (int nk = 0; nk < 2; ++nk)
            for (int r = 0; r < 4; ++r) {
              float pv = __expf(sc[mi][nk][r] - mnew);
              sc[mi][nk][r] = pv;
              rs += pv;
            }
        } else {
          for (int nk = 0; nk < 2; ++nk)
            for (int r = 0; r < 4; ++r) {
              float pv = sc[mi][nk][r];
              pv = (pv <= -1e29f) ? 0.f : __expf(pv - mnew);  // guard: mnew may be -1e30
              sc[mi][nk][r] = pv;
              rs += pv;
            }
        }
        rs += __shfl_xor(rs, 16);
        rs += __shfl_xor(rs, 32);
        const float alpha = __expf(mrun[mi] - mnew);
        mrun[mi] = mnew;
        lrun[mi] = lrun[mi] * alpha + rs;
        for (int nd = 0; nd < 8; ++nd)
          for (int r = 0; r < 4; ++r) accO[mi][nd][r] *= alpha;
        for (int nk = 0; nk < 2; ++nk) {
          u16x4 o;
          for (int r = 0; r < 4; ++r) o[r] = f2bf(sc[mi][nk][r]);
          *(u16x4*)&myPs[(mi * 16 + cc) * 40 + nk * 16 + g * 4] = o;
        }
      }

      __builtin_amdgcn_s_setprio(1);
      {
        s16x8 pa[2];
        for (int mi = 0; mi < 2; ++mi)
          pa[mi] = *(const s16x8*)&myPs[(mi * 16 + cc) * 40 + g * 8];
        for (int nd = 0; nd < 8; ++nd) {
          const int d = nd * 16 + cc;
          s16x8 vb = *(const s16x8*)&Vl[cur][d * 32 + ((g ^ (d & 3)) * 8)];
          for (int mi = 0; mi < 2; ++mi)
            accO[mi][nd] = __builtin_amdgcn_mfma_f32_16x16x32_bf16(vb, pa[mi], accO[mi][nd], 0, 0, 0);
        }
      }
      __builtin_amdgcn_s_setprio(0);
    }

    __syncthreads();
    cur ^= 1;
  }

  u16* op = AO + ((size_t)b * 4096 + q0) * 2048 + (size_t)h * 128;
  for (int mi = 0; mi < 2; ++mi) {
    const float inv = 1.0f / lrun[mi];
    for (int nd = 0; nd < 8; ++nd) {
      u16x4 o;
      for (int r = 0; r < 4; ++r) o[r] = f2bf(accO[mi][nd][r] * inv);
      *(u16x4*)(op + (size_t)(w * 32 + mi * 16 + cc) * 2048 + nd * 16 + g * 4) = o;
    }
  }
}

extern "C" void kernel_launch(void* const* d_in, const int* in_sizes, int n_in,
                              void* d_out, int out_size, void* d_ws, size_t ws_size,
                              hipStream_t stream) {
  const float* emb  = (const float*)d_in[0];
  const float* cosb = (const float*)d_in[1];
  const float* sinb = (const float*)d_in[2];
  const float* wq   = (const float*)d_in[3];
  const float* wk   = (const float*)d_in[4];
  const float* wv   = (const float*)d_in[5];
  const float* wo   = (const float*)d_in[6];
  float* out = (float*)d_out;

  char* ws = (char*)d_ws;
  size_t off = 0;
  auto alloc = [&](size_t bytes) -> void* {
    void* p = ws + off;
    off += (bytes + 255) & ~(size_t)255;
    return p;
  };
  u16* X   = (u16*)alloc((size_t)8192 * 2048 * 2);   // normed bf16; reused as attn_out
  u16* Wt  = (u16*)alloc((size_t)3072 * 2048 * 2);   // [wq|wk|wv] transposed [n][k]
  u16* Wot = (u16*)alloc((size_t)2048 * 2048 * 2);   // wo transposed
  u16* Qb  = (u16*)alloc((size_t)2 * 16 * 4096 * 128 * 2);
  u16* Kb  = (u16*)alloc((size_t)2 * 4 * 4096 * 128 * 2);
  u16* VtB = (u16*)alloc((size_t)2 * 4 * 128 * 4096 * 2);  // V transposed [b][hkv][d][s]
  u16* AOb = X;  // X dead after GEMM1

  k_transpose<<<dim3(64, 64), 256, 0, stream>>>(wq, Wt, 2048, 2048);
  k_transpose<<<dim3(16, 64), 256, 0, stream>>>(wk, Wt + (size_t)2048 * 2048, 512, 2048);
  k_transpose<<<dim3(16, 64), 256, 0, stream>>>(wv, Wt + (size_t)2560 * 2048, 512, 2048);
  k_transpose<<<dim3(64, 64), 256, 0, stream>>>(wo, Wot, 2048, 2048);
  k_rmsnorm<<<8192, 256, 0, stream>>>(emb, X);
  // GEMM1: 8192x3072x2048, fused RoPE epilogue -> writes Qb/Kb/VtB directly (no qkv)
  k_gemm256<0><<<dim3(384), 512, 0, stream>>>(X, Wt, 3072, 2048, 12, cosb, sinb, Qb, Kb, VtB,
                                              nullptr, nullptr);
  k_attn<<<dim3(1024), 256, 0, stream>>>(Qb, Kb, VtB, AOb);
  // GEMM2: 8192x2048x2048 -> f32 out + residual
  k_gemm256<1><<<dim3(256), 512, 0, stream>>>(AOb, Wot, 2048, 2048, 8, nullptr, nullptr, nullptr, nullptr,
                                              nullptr, emb, out);
}

// Round 18
// 336.186 us; speedup vs baseline: 1.0689x; 1.0562x over previous
//
#include <hip/hip_runtime.h>

typedef unsigned short u16;
typedef __attribute__((ext_vector_type(8))) short s16x8;
typedef __attribute__((ext_vector_type(8))) unsigned short u16x8;
typedef __attribute__((ext_vector_type(4))) unsigned short u16x4;
typedef __attribute__((ext_vector_type(4))) float f32x4;

#define DEV __device__ __forceinline__

DEV u16 f2bf(float x) {
  union { float f; unsigned u; } c; c.f = x;
  unsigned r = c.u + 0x7FFFu + ((c.u >> 16) & 1u);
  return (u16)(r >> 16);
}
DEV float bf2f(u16 u) {
  union { unsigned u; float f; } c; c.u = ((unsigned)u) << 16;
  return c.f;
}
DEV void gload_lds16(const void* g, void* l) {
  __builtin_amdgcn_global_load_lds((const __attribute__((address_space(1))) void*)g,
                                   (__attribute__((address_space(3))) void*)l, 16, 0, 0);
}

// ---------------- RMSNorm: f32 [8192][2048] -> bf16 X ----------------
__global__ __launch_bounds__(256) void k_rmsnorm(const float* __restrict__ emb, u16* __restrict__ X) {
  const int row = blockIdx.x;
  const int t = threadIdx.x;
  const float4* p4 = (const float4*)(emb + (size_t)row * 2048);
  float4 v0 = p4[t * 2], v1 = p4[t * 2 + 1];
  float ss = v0.x * v0.x + v0.y * v0.y + v0.z * v0.z + v0.w * v0.w
           + v1.x * v1.x + v1.y * v1.y + v1.z * v1.z + v1.w * v1.w;
  for (int off = 32; off; off >>= 1) ss += __shfl_xor(ss, off);
  __shared__ float red[4];
  if ((t & 63) == 0) red[t >> 6] = ss;
  __syncthreads();
  float tot = red[0] + red[1] + red[2] + red[3];
  float inv = rsqrtf(tot * (1.0f / 2048.0f) + 1e-5f);
  float v[8] = {v0.x, v0.y, v0.z, v0.w, v1.x, v1.y, v1.z, v1.w};
  u16x8 o;
  for (int j = 0; j < 8; ++j) o[j] = f2bf(v[j] * inv);
  *(u16x8*)(X + (size_t)row * 2048 + t * 8) = o;
}

// ------------- transpose f32 [R][C] -> bf16 [C][dstStride] -------------
__global__ __launch_bounds__(256) void k_transpose(const float* __restrict__ src, u16* __restrict__ dst,
                                                   int C, int dstStride) {
  __shared__ float tile[32][33];
  const int bc = blockIdx.x * 32, br = blockIdx.y * 32;
  const int tx = threadIdx.x & 31, ty = threadIdx.x >> 5;
  for (int i = 0; i < 32; i += 8)
    tile[ty + i][tx] = src[(size_t)(br + ty + i) * C + bc + tx];
  __syncthreads();
  for (int i = 0; i < 32; i += 8)
    dst[(size_t)(bc + ty + i) * dstStride + br + tx] = f2bf(tile[tx][ty + i]);
}

// ------------- GEMM 256x256 tile, BK=64, 8 waves, barrier-free interior (R12/R15, FROZEN) -------------
// Measured best. Four pipelining attempts (R8/R10/R16) and the R17 epilogue hoist all
// regressed; this exact text measured 340us total. Do not touch.
// colmap(ni) = wn*16 + ni*64: RoPE (d,d+64) pairs land in one thread's acc registers.
template <int EPI>
__global__ __launch_bounds__(512) void k_gemm256(const u16* __restrict__ A, const u16* __restrict__ Bt,
                                                 const int N, const int K, const int NBN,
                                                 const float* __restrict__ cosb, const float* __restrict__ sinb,
                                                 u16* __restrict__ Qb, u16* __restrict__ Kb,
                                                 u16* __restrict__ VtOut,
                                                 const float* __restrict__ Emb, float* __restrict__ Cf) {
  __shared__ u16 Asm[2][256 * 64];
  __shared__ u16 Bsm[2][256 * 64];
  const int t = threadIdx.x, w = t >> 6, l = t & 63, g = (l >> 4), cc = l & 15;
  const int wm = w >> 2, wn = w & 3;

  const int lin = blockIdx.x;                  // natural order (best measured L2 behavior)
  const int bm = lin / NBN, bn = lin % NBN;
  const size_t m0 = (size_t)bm * 256, n0 = (size_t)bn * 256;

  const int srow = t >> 3, sch = t & 7;        // staging: row-within-64, 16B chunk

  auto stA = [&](int kt, int p, int pass) {
    const int row = pass * 64 + srow;
    const int c2 = sch ^ (row & 7);
    gload_lds16(A + (m0 + row) * K + kt * 64 + c2 * 8, &Asm[p][row * 64 + sch * 8]);
  };
  auto stB = [&](int kt, int p, int pass) {
    const int row = pass * 64 + srow;
    const int c2 = sch ^ (row & 7);
    gload_lds16(Bt + (n0 + row) * K + kt * 64 + c2 * 8, &Bsm[p][row * 64 + sch * 8]);
  };

  f32x4 acc[8][4];
#pragma unroll
  for (int mi = 0; mi < 8; ++mi)
#pragma unroll
    for (int ni = 0; ni < 4; ++ni) acc[mi][ni] = (f32x4){0.f, 0.f, 0.f, 0.f};

  const int NT = K >> 6;
#pragma unroll
  for (int pass = 0; pass < 4; ++pass) { stA(0, 0, pass); stB(0, 0, pass); }
  __syncthreads();

  for (int kt = 0; kt < NT; ++kt) {
    const int p = kt & 1;
    const bool pf = (kt + 1 < NT);
    const u16* Ap = &Asm[p][0];
    const u16* Bp = &Bsm[p][0];

    s16x8 bf[2][4];
#pragma unroll
    for (int kk = 0; kk < 2; ++kk)
#pragma unroll
      for (int ni = 0; ni < 4; ++ni) {
        const int row = wn * 16 + ni * 64 + cc;        // colmap
        bf[kk][ni] = *(const s16x8*)&Bp[row * 64 + (((kk * 4 + g) ^ (row & 7)) * 8)];
      }

#pragma unroll
    for (int q = 0; q < 4; ++q) {
      s16x8 af[2][2];
#pragma unroll
      for (int kk = 0; kk < 2; ++kk)
#pragma unroll
        for (int m2 = 0; m2 < 2; ++m2) {
          const int row = wm * 128 + (q * 2 + m2) * 16 + cc;
          af[kk][m2] = *(const s16x8*)&Ap[row * 64 + (((kk * 4 + g) ^ (row & 7)) * 8)];
        }
      if (pf) {   // 3/3/2/0 spread
        if (q == 0) { stA(kt + 1, p ^ 1, 0); stA(kt + 1, p ^ 1, 1); stB(kt + 1, p ^ 1, 0); }
        else if (q == 1) { stA(kt + 1, p ^ 1, 2); stA(kt + 1, p ^ 1, 3); stB(kt + 1, p ^ 1, 1); }
        else if (q == 2) { stB(kt + 1, p ^ 1, 2); stB(kt + 1, p ^ 1, 3); }
      }
      // barrier-free interior: compiler interleaves ds_read/MFMA/staging
#pragma unroll
      for (int m2 = 0; m2 < 2; ++m2)
#pragma unroll
        for (int ni = 0; ni < 4; ++ni)
#pragma unroll
          for (int kk = 0; kk < 2; ++kk)
            acc[q * 2 + m2][ni] =
                __builtin_amdgcn_mfma_f32_16x16x32_bf16(af[kk][m2], bf[kk][ni], acc[q * 2 + m2][ni], 0, 0, 0);
    }
    __syncthreads();   // the only barrier per tile
  }

  if (EPI == 1) {
#pragma unroll
    for (int mi = 0; mi < 8; ++mi)
#pragma unroll
      for (int ni = 0; ni < 4; ++ni)
#pragma unroll
        for (int r = 0; r < 4; ++r) {
          const size_t row = m0 + wm * 128 + mi * 16 + g * 4 + r;
          const size_t col = n0 + wn * 16 + ni * 64 + cc;
          Cf[row * N + col] = acc[mi][ni][r] + Emb[row * N + col];
        }
  } else if ((int)n0 < 2560) {
    // Q or K region: in-register RoPE on pairs (ni=2p, ni=2p+1), direct scatter.
    const bool isK = (int)n0 >= 2048;
    const float* cbase = cosb + (isK ? 524288 : 0);
    const float* sbase = sinb + (isK ? 524288 : 0);
    const int dlo = wn * 16 + cc;              // d in [0,64)
#pragma unroll
    for (int mi = 0; mi < 8; ++mi)
#pragma unroll
      for (int p = 0; p < 2; ++p) {
        const int colbase = (int)n0 + p * 128;   // head base col
#pragma unroll
        for (int r = 0; r < 4; ++r) {
          const int row = (int)m0 + wm * 128 + mi * 16 + g * 4 + r;
          const int bb = row >> 12, s = row & 4095;
          const float lo = acc[mi][2 * p + 0][r];
          const float hi = acc[mi][2 * p + 1][r];
          const float* cpr = cbase + (size_t)s * 128;
          const float* spr = sbase + (size_t)s * 128;
          const u16 olo = f2bf(cpr[dlo] * lo + spr[dlo] * hi);
          const u16 ohi = f2bf(cpr[dlo + 64] * hi + spr[dlo + 64] * lo);
          if (!isK) {
            const int h = colbase >> 7;          // 0..15
            u16* dq = Qb + ((size_t)(bb * 16 + h) * 4096 + s) * 128;
            dq[dlo] = olo;
            dq[dlo + 64] = ohi;
          } else {
            const int hkv = (colbase - 2048) >> 7;   // 0..3
            u16* dk = Kb + ((size_t)(bb * 4 + hkv) * 4096 + s) * 128;
            dk[dlo] = olo;
            dk[dlo + 64] = ohi;
          }
        }
      }
  } else {
    // V region: write V transposed Vt[b][hkv][d][4096]
    const int bb = (int)(m0 >> 12);
    const int s0base = (int)(m0 & 4095);
#pragma unroll
    for (int mi = 0; mi < 8; ++mi)
#pragma unroll
      for (int ni = 0; ni < 4; ++ni) {
        const int dcol = (int)(n0 - 2560) + wn * 16 + ni * 64 + cc;   // 0..511
        const int hkv = dcol >> 7, d = dcol & 127;
        const int s = s0base + wm * 128 + mi * 16 + g * 4;
        u16x4 o;
#pragma unroll
        for (int r = 0; r < 4; ++r) o[r] = f2bf(acc[mi][ni][r]);
        *(u16x4*)(VtOut + ((size_t)(bb * 4 + hkv) * 128 + d) * 4096 + s) = o;
      }
  }
}

// ------------- sliding-window flash attention, per-wave tile skip + fast path (R14) -------------
__global__ __launch_bounds__(256) void k_attn(const u16* __restrict__ Q, const u16* __restrict__ K,
                                              const u16* __restrict__ Vt, u16* __restrict__ AO) {
  const int bid = blockIdx.x;
  const int lin = (bid & 7) * 128 + (bid >> 3);   // XCD-pinned: group = bid&7
  const int grp = lin >> 7;
  const int b = grp >> 2, hkv = grp & 3;
  const int rem = lin & 127;
  const int h = hkv * 4 + (rem >> 5);
  const int qt = rem & 31;

  const int t = threadIdx.x, w = t >> 6, l = t & 63, g = l >> 4, cc = l & 15;
  const int q0 = qt * 128;
  const int myq0 = q0 + w * 32;                   // this wave's 32 q-rows
  const u16* Qp = Q + (((size_t)b * 16 + h) * 4096 + q0) * 128;
  const u16* Kp = K + ((size_t)b * 4 + hkv) * 4096 * 128;
  const u16* Vp = Vt + ((size_t)b * 4 + hkv) * 128 * 4096;

  __shared__ u16 Kl[2][32 * 128];   // [key][d], swizzled chunks (^row&7)
  __shared__ u16 Vl[2][128 * 32];   // [d][key], swizzled chunks (^d&3)
  __shared__ u16 Ps[4][32 * 40];    // per-wave P, stride 40 u16
  u16* myPs = &Ps[w][0];

  auto stage = [&](int kt, int bufi) {
    for (int pass = 0; pass < 2; ++pass) {
      const int m = pass * 256 + t;
      const int row = m >> 4, cst = m & 15;
      const int cor = cst ^ (row & 7);
      gload_lds16(Kp + (size_t)(kt * 32 + row) * 128 + cor * 8, &Kl[bufi][m * 8]);
    }
    for (int pass = 0; pass < 2; ++pass) {
      const int m = pass * 256 + t;
      const int d = m >> 2, cst = m & 3;
      const int cor = cst ^ (d & 3);
      gload_lds16(Vp + (size_t)d * 4096 + kt * 32 + cor * 8, &Vl[bufi][m * 8]);
    }
  };

  s16x8 qf[2][4];
  for (int mi = 0; mi < 2; ++mi)
    for (int kk = 0; kk < 4; ++kk)
      qf[mi][kk] = *(const s16x8*)(Qp + (size_t)(w * 32 + mi * 16 + cc) * 128 + kk * 32 + g * 8);

  f32x4 accO[2][8];
  for (int mi = 0; mi < 2; ++mi)
    for (int nd = 0; nd < 8; ++nd) accO[mi][nd] = (f32x4){0.f, 0.f, 0.f, 0.f};
  float mrun[2], lrun[2];
  for (int mi = 0; mi < 2; ++mi) { mrun[mi] = -1e30f; lrun[mi] = 0.f; }

  int lo = q0 - 511; if (lo < 0) lo = 0;
  const int kt_lo = lo >> 5, kt_hi = (q0 + 127) >> 5;
  const float scale = 0.08838834764831845f;

  int cur = 0;
  stage(kt_lo, 0);
  __syncthreads();

  for (int kt = kt_lo; kt <= kt_hi; ++kt) {
    if (kt < kt_hi) stage(kt + 1, cur ^ 1);

    const int k0 = kt * 32;
    const bool haswork = (k0 <= myq0 + 31) && (k0 + 31 >= myq0 - 511);
    const bool fullw   = (k0 + 31 <= myq0) && (k0 >= myq0 - 480);

    if (haswork) {
      f32x4 sc[2][2];
      for (int mi = 0; mi < 2; ++mi)
        for (int nk = 0; nk < 2; ++nk) sc[mi][nk] = (f32x4){0.f, 0.f, 0.f, 0.f};
      __builtin_amdgcn_s_setprio(1);
      for (int kk = 0; kk < 4; ++kk) {
        s16x8 kb[2];
        for (int nk = 0; nk < 2; ++nk) {
          const int row = nk * 16 + cc;
          kb[nk] = *(const s16x8*)&Kl[cur][row * 128 + (((kk * 4 + g) ^ (row & 7)) * 8)];
        }
        for (int mi = 0; mi < 2; ++mi)
          for (int nk = 0; nk < 2; ++nk)
            sc[mi][nk] = __builtin_amdgcn_mfma_f32_16x16x32_bf16(kb[nk], qf[mi][kk], sc[mi][nk], 0, 0, 0);
      }
      __builtin_amdgcn_s_setprio(0);

      for (int mi = 0; mi < 2; ++mi) {
        const int qpos = myq0 + mi * 16 + cc;
        if (fullw) {
          for (int nk = 0; nk < 2; ++nk)
            for (int r = 0; r < 4; ++r) sc[mi][nk][r] *= scale;
        } else {
          for (int nk = 0; nk < 2; ++nk)
            for (int r = 0; r < 4; ++r) {
              const int kpos = k0 + nk * 16 + g * 4 + r;
              const float v = sc[mi][nk][r] * scale;
              sc[mi][nk][r] = (kpos <= qpos && kpos + 512 > qpos) ? v : -1e30f;
            }
        }
        float rm = sc[mi][0][0];
        for (int nk = 0; nk < 2; ++nk)
          for (int r = 0; r < 4; ++r) rm = fmaxf(rm, sc[mi][nk][r]);
        rm = fmaxf(rm, __shfl_xor(rm, 16));
        rm = fmaxf(rm, __shfl_xor(rm, 32));
        const float mnew = fmaxf(mrun[mi], rm);
        float rs = 0.f;
        if (fullw) {
          for (int nk = 0; nk < 2; ++nk)
            for (int r = 0; r < 4; ++r) {
              float pv = __expf(sc[mi][nk][r] - mnew);
              sc[mi][nk][r] = pv;
              rs += pv;
            }
        } else {
          for (int nk = 0; nk < 2; ++nk)
            for (int r = 0; r < 4; ++r) {
              float pv = sc[mi][nk][r];
              pv = (pv <= -1e29f) ? 0.f : __expf(pv - mnew);  // guard: mnew may be -1e30
              sc[mi][nk][r] = pv;
              rs += pv;
            }
        }
        rs += __shfl_xor(rs, 16);
        rs += __shfl_xor(rs, 32);
        const float alpha = __expf(mrun[mi] - mnew);
        mrun[mi] = mnew;
        lrun[mi] = lrun[mi] * alpha + rs;
        for (int nd = 0; nd < 8; ++nd)
          for (int r = 0; r < 4; ++r) accO[mi][nd][r] *= alpha;
        for (int nk = 0; nk < 2; ++nk) {
          u16x4 o;
          for (int r = 0; r < 4; ++r) o[r] = f2bf(sc[mi][nk][r]);
          *(u16x4*)&myPs[(mi * 16 + cc) * 40 + nk * 16 + g * 4] = o;
        }
      }

      __builtin_amdgcn_s_setprio(1);
      {
        s16x8 pa[2];
        for (int mi = 0; mi < 2; ++mi)
          pa[mi] = *(const s16x8*)&myPs[(mi * 16 + cc) * 40 + g * 8];
        for (int nd = 0; nd < 8; ++nd) {
          const int d = nd * 16 + cc;
          s16x8 vb = *(const s16x8*)&Vl[cur][d * 32 + ((g ^ (d & 3)) * 8)];
          for (int mi = 0; mi < 2; ++mi)
            accO[mi][nd] = __builtin_amdgcn_mfma_f32_16x16x32_bf16(vb, pa[mi], accO[mi][nd], 0, 0, 0);
        }
      }
      __builtin_amdgcn_s_setprio(0);
    }

    __syncthreads();
    cur ^= 1;
  }

  u16* op = AO + ((size_t)b * 4096 + q0) * 2048 + (size_t)h * 128;
  for (int mi = 0; mi < 2; ++mi) {
    const float inv = 1.0f / lrun[mi];
    for (int nd = 0; nd < 8; ++nd) {
      u16x4 o;
      for (int r = 0; r < 4; ++r) o[r] = f2bf(accO[mi][nd][r] * inv);
      *(u16x4*)(op + (size_t)(w * 32 + mi * 16 + cc) * 2048 + nd * 16 + g * 4) = o;
    }
  }
}

extern "C" void kernel_launch(void* const* d_in, const int* in_sizes, int n_in,
                              void* d_out, int out_size, void* d_ws, size_t ws_size,
                              hipStream_t stream) {
  const float* emb  = (const float*)d_in[0];
  const float* cosb = (const float*)d_in[1];
  const float* sinb = (const float*)d_in[2];
  const float* wq   = (const float*)d_in[3];
  const float* wk   = (const float*)d_in[4];
  const float* wv   = (const float*)d_in[5];
  const float* wo   = (const float*)d_in[6];
  float* out = (float*)d_out;

  char* ws = (char*)d_ws;
  size_t off = 0;
  auto alloc = [&](size_t bytes) -> void* {
    void* p = ws + off;
    off += (bytes + 255) & ~(size_t)255;
    return p;
  };
  u16* X   = (u16*)alloc((size_t)8192 * 2048 * 2);   // normed bf16; reused as attn_out
  u16* Wt  = (u16*)alloc((size_t)3072 * 2048 * 2);   // [wq|wk|wv] transposed [n][k]
  u16* Wot = (u16*)alloc((size_t)2048 * 2048 * 2);   // wo transposed
  u16* Qb  = (u16*)alloc((size_t)2 * 16 * 4096 * 128 * 2);
  u16* Kb  = (u16*)alloc((size_t)2 * 4 * 4096 * 128 * 2);
  u16* VtB = (u16*)alloc((size_t)2 * 4 * 128 * 4096 * 2);  // V transposed [b][hkv][d][s]
  u16* AOb = X;  // X dead after GEMM1

  k_transpose<<<dim3(64, 64), 256, 0, stream>>>(wq, Wt, 2048, 2048);
  k_transpose<<<dim3(16, 64), 256, 0, stream>>>(wk, Wt + (size_t)2048 * 2048, 512, 2048);
  k_transpose<<<dim3(16, 64), 256, 0, stream>>>(wv, Wt + (size_t)2560 * 2048, 512, 2048);
  k_transpose<<<dim3(64, 64), 256, 0, stream>>>(wo, Wot, 2048, 2048);
  k_rmsnorm<<<8192, 256, 0, stream>>>(emb, X);
  // GEMM1: 8192x3072x2048, fused RoPE epilogue -> writes Qb/Kb/VtB directly (no qkv)
  k_gemm256<0><<<dim3(384), 512, 0, stream>>>(X, Wt, 3072, 2048, 12, cosb, sinb, Qb, Kb, VtB,
                                              nullptr, nullptr);
  k_attn<<<dim3(1024), 256, 0, stream>>>(Qb, Kb, VtB, AOb);
  // GEMM2: 8192x2048x2048 -> f32 out + residual
  k_gemm256<1><<<dim3(256), 512, 0, stream>>>(AOb, Wot, 2048, 2048, 8, nullptr, nullptr, nullptr, nullptr,
                                              nullptr, emb, out);
}